// Round 1
// baseline (1241.404 us; speedup 1.0000x reference)
//
#include <hip/hip_runtime.h>
#include <cstddef>

// Problem constants
#define Dn 256
#define Ln 64
#define Kn 64
#define Pn 8
#define Fn 104
#define Cn 500
#define KF 6656          // Kn*Fn
#define TPB 448          // 7 waves

#define WMLD 112         // Wm LDS row stride (padded from 104)
#define XTLD 68          // XT LDS row stride (padded from 64)

// XOR-swizzled XT addressing: 4-word groups permuted by f to spread banks.
__device__ __forceinline__ int xt_word(int f, int k) {
  return f * XTLD + ((((k >> 2) ^ (f & 15)) << 2) | (k & 3));
}

// One GEMM pass: acc[ri][ji] += sum_{f in s-segment} XT[f][r0+ri] * WMs[wmRow0+f][j0+ji]
__device__ __forceinline__ void gemm_pass(const float* __restrict__ XTs,
                                          const float* __restrict__ WMs,
                                          int wmRow0, int s, int r0, int j0,
                                          float acc[8][8]) {
  const int fbeg = s * 26;
  const int q0 = r0 >> 2;          // k-quad index of rows r0..r0+3
  #pragma unroll 2
  for (int u = 0; u < 26; ++u) {
    const int f = fbeg + u;
    const int sw = f & 15;
    const float4 A0 = *reinterpret_cast<const float4*>(XTs + f * XTLD + (((q0)     ^ sw) << 2));
    const float4 A1 = *reinterpret_cast<const float4*>(XTs + f * XTLD + (((q0 + 1) ^ sw) << 2));
    const float4 B0 = *reinterpret_cast<const float4*>(WMs + (wmRow0 + f) * WMLD + j0);
    const float4 B1 = *reinterpret_cast<const float4*>(WMs + (wmRow0 + f) * WMLD + j0 + 4);
    const float a[8] = {A0.x, A0.y, A0.z, A0.w, A1.x, A1.y, A1.z, A1.w};
    const float b[8] = {B0.x, B0.y, B0.z, B0.w, B1.x, B1.y, B1.z, B1.w};
    #pragma unroll
    for (int ri = 0; ri < 8; ++ri)
      #pragma unroll
      for (int ji = 0; ji < 8; ++ji)
        acc[ri][ji] = fmaf(a[ri], b[ji], acc[ri][ji]);
  }
}

// Reduce s-partials via shfl, add bias, relu, write PREV rows.
__device__ __forceinline__ void gemm_epilogue(float acc[8][8],
                                              const float* __restrict__ bms,
                                              float* __restrict__ PREVs,
                                              int s, int r0, int j0, bool jact) {
  #pragma unroll
  for (int ri = 0; ri < 8; ++ri) {
    #pragma unroll
    for (int ji = 0; ji < 8; ++ji) {
      float x = acc[ri][ji];
      x += __shfl_xor(x, 16, 64);
      x += __shfl_xor(x, 32, 64);
      acc[ri][ji] = x;
    }
  }
  if (s == 0 && jact) {
    #pragma unroll
    for (int ri = 0; ri < 8; ++ri) {
      float4 o0, o1;
      o0.x = fmaxf(acc[ri][0] + bms[j0 + 0], 0.f);
      o0.y = fmaxf(acc[ri][1] + bms[j0 + 1], 0.f);
      o0.z = fmaxf(acc[ri][2] + bms[j0 + 2], 0.f);
      o0.w = fmaxf(acc[ri][3] + bms[j0 + 3], 0.f);
      o1.x = fmaxf(acc[ri][4] + bms[j0 + 4], 0.f);
      o1.y = fmaxf(acc[ri][5] + bms[j0 + 5], 0.f);
      o1.z = fmaxf(acc[ri][6] + bms[j0 + 6], 0.f);
      o1.w = fmaxf(acc[ri][7] + bms[j0 + 7], 0.f);
      *reinterpret_cast<float4*>(PREVs + (r0 + ri) * Fn + j0)     = o0;
      *reinterpret_cast<float4*>(PREVs + (r0 + ri) * Fn + j0 + 4) = o1;
    }
  }
}

// Persistent scan kernel: one block per d, loops l = 0..63 internally.
__global__ __launch_bounds__(TPB) void scan_kernel(
    const float* __restrict__ af,     // (D, L, K, F)
    const int*   __restrict__ pidx,   // (D, L-1, K, P)
    const float* __restrict__ W1, const float* __restrict__ b1,
    const float* __restrict__ Wm, const float* __restrict__ bm,
    const float* __restrict__ att_w,
    float* __restrict__ sink)         // (D, F) out
{
  extern __shared__ float smem[];
  float* WMs   = smem;                       // 208*112 = 23296 floats
  float* XTs   = WMs + 208 * WMLD;           // 104*68  = 7072
  float* PREVs = XTs + Fn * XTLD;            // 64*104  = 6656
  float* bms   = PREVs + Kn * Fn;            // 112
  float* aws   = bms + WMLD;                 // 104
  int*   idxs  = (int*)(aws + Fn);           // 512 ints
  // total = (23296+7072+6656+112+104+512)*4 = 151008 B

  const int t = threadIdx.x;
  const int d = blockIdx.x;
  const int lane = t & 63;
  const int w = t >> 6;
  const int tile = w * 16 + (lane & 15);     // 0..111
  const int s = lane >> 4;                   // 0..3 (f-split)
  const int rt = tile & 7;                   // 0..7
  const int jt = tile >> 3;                  // 0..13
  const int r0 = rt << 3;
  const int j0 = jt << 3;
  const bool jact = (j0 < Fn);               // jt==13 computes into pad, never writes

  const float* afd = af + (size_t)d * (Ln * KF);
  const int*   pid = pidx + (size_t)d * ((Ln - 1) * Kn * Pn);

  // ---- stage W1 (+pad), b1, att_w, atoms(l=0) transposed ----
  for (int i = t; i < Fn * Fn; i += TPB) {
    int r = i / Fn, c = i - r * Fn;
    WMs[r * WMLD + c] = W1[i];
  }
  for (int i = t; i < 208 * 8; i += TPB) {   // zero pad columns 104..111
    int r = i >> 3, c = Fn + (i & 7);
    WMs[r * WMLD + c] = 0.f;
  }
  if (t < Fn) { bms[t] = b1[t]; aws[t] = att_w[t]; }
  if (t >= Fn && t < WMLD) bms[t] = 0.f;
  for (int i = t; i < KF; i += TPB) {
    int k = i / Fn, f = i - k * Fn;
    XTs[xt_word(f, k)] = afd[i];             // block l=0
  }
  __syncthreads();

  // ---- step 0: PREV = relu(atoms0 @ W1 + b1) ----
  {
    float acc[8][8];
    #pragma unroll
    for (int ri = 0; ri < 8; ++ri)
      #pragma unroll
      for (int ji = 0; ji < 8; ++ji) acc[ri][ji] = 0.f;
    gemm_pass(XTs, WMs, 0, s, r0, j0, acc);
    gemm_epilogue(acc, bms, PREVs, s, r0, j0, jact);
  }
  __syncthreads();

  // ---- restage Wm, bm; idx block 0 -> LDS; prefetch atoms(1), idx block 1 ----
  for (int i = t; i < 208 * Fn; i += TPB) {
    int r = i / Fn, c = i - r * Fn;
    WMs[r * WMLD + c] = Wm[i];
  }
  if (t < Fn) bms[t] = bm[t];
  idxs[t] = pid[t];
  if (t < 64) idxs[TPB + t] = pid[TPB + t];

  float pf[15];
  #pragma unroll
  for (int u2 = 0; u2 < 15; ++u2) {
    int i = u2 * TPB + t;
    pf[u2] = (i < KF) ? afd[KF + i] : 0.f;   // atoms block l=1
  }
  int ir0 = pid[512 + t];                    // idx block 1
  int ir1 = (t < 64) ? pid[512 + TPB + t] : 0;
  __syncthreads();

  // ---- main scan: l = 1..63 ----
  for (int l = 1; l < Ln; ++l) {
    // A: gather + softmax(P) + aggregate -> XT (transposed, swizzled)
    for (int q = t; q < Kn * (Fn / 4); q += TPB) {   // 1664 quads
      int k = q / 26, fq = (q - k * 26) << 2;
      const float4 w4 = *reinterpret_cast<const float4*>(aws + fq);
      const float wa[4] = {w4.x, w4.y, w4.z, w4.w};
      float vv[8][4];
      #pragma unroll
      for (int p = 0; p < Pn; ++p) {
        int ip = idxs[(k << 3) + p];
        float4 v4 = *reinterpret_cast<const float4*>(PREVs + ip * Fn + fq);
        vv[p][0] = v4.x; vv[p][1] = v4.y; vv[p][2] = v4.z; vv[p][3] = v4.w;
      }
      float ag[4];
      #pragma unroll
      for (int c = 0; c < 4; ++c) {
        float m = -3.0e38f;
        #pragma unroll
        for (int p = 0; p < Pn; ++p) m = fmaxf(m, wa[c] * vv[p][c]);
        float es = 0.f, ps = 0.f;
        #pragma unroll
        for (int p = 0; p < Pn; ++p) {
          float e = __expf(wa[c] * vv[p][c] - m);
          es += e; ps += e * vv[p][c];
        }
        ag[c] = ps / es;
      }
      #pragma unroll
      for (int c = 0; c < 4; ++c) XTs[xt_word(fq + c, k)] = ag[c];
    }
    __syncthreads();  // B

    // C: GEMM pass A (agg @ Wm_top)
    float acc[8][8];
    #pragma unroll
    for (int ri = 0; ri < 8; ++ri)
      #pragma unroll
      for (int ji = 0; ji < 8; ++ji) acc[ri][ji] = 0.f;
    gemm_pass(XTs, WMs, 0, s, r0, j0, acc);
    __syncthreads();  // D

    // E: write prefetched atoms(l) -> XT; idx block l -> LDS; prefetch l+1
    #pragma unroll
    for (int u2 = 0; u2 < 15; ++u2) {
      int i = u2 * TPB + t;
      if (i < KF) {
        int k = i / Fn, f = i - k * Fn;
        XTs[xt_word(f, k)] = pf[u2];
      }
    }
    if (l < 63) {
      idxs[t] = ir0;
      if (t < 64) idxs[TPB + t] = ir1;
      const float* an = afd + (size_t)(l + 1) * KF;
      #pragma unroll
      for (int u2 = 0; u2 < 15; ++u2) {
        int i = u2 * TPB + t;
        pf[u2] = (i < KF) ? an[i] : 0.f;
      }
      if (l < 62) {
        const int* pn = pid + (size_t)(l + 1) * 512;
        ir0 = pn[t];
        if (t < 64) ir1 = pn[TPB + t];
      }
    }
    __syncthreads();  // F

    // G: GEMM pass B (atoms @ Wm_bot) + epilogue -> PREV
    gemm_pass(XTs, WMs, Fn, s, r0, j0, acc);
    gemm_epilogue(acc, bms, PREVs, s, r0, j0, jact);
    __syncthreads();  // H
  }

  // sink = last[:, K-1]
  if (t < Fn) sink[d * Fn + t] = PREVs[(Kn - 1) * Fn + t];
}

// Final: DAG softmax over D, pool, project to C.
__global__ __launch_bounds__(512) void final_kernel(
    const float* __restrict__ sink, const float* __restrict__ dag_w,
    const float* __restrict__ Wf, const float* __restrict__ bf,
    float* __restrict__ out)
{
  extern __shared__ float smem[];
  float* ss = smem;               // 256*104
  float* pooled = ss + Dn * Fn;   // 104
  const int t = threadIdx.x;
  for (int i = t; i < Dn * Fn; i += 512) ss[i] = sink[i];
  __syncthreads();
  if (t < Fn) {
    float wv = dag_w[t];
    float m = -3.0e38f;
    for (int dd = 0; dd < Dn; ++dd) m = fmaxf(m, wv * ss[dd * Fn + t]);
    float es = 0.f, ps = 0.f;
    for (int dd = 0; dd < Dn; ++dd) {
      float v = ss[dd * Fn + t];
      float e = __expf(wv * v - m);
      es += e; ps += e * v;
    }
    pooled[t] = ps / es;
  }
  __syncthreads();
  if (t < Cn) {
    float a = bf[t];
    for (int f = 0; f < Fn; ++f) a = fmaf(pooled[f], Wf[f * Cn + t], a);
    out[t] = a;
  }
}

extern "C" void kernel_launch(void* const* d_in, const int* in_sizes, int n_in,
                              void* d_out, int out_size, void* d_ws, size_t ws_size,
                              hipStream_t stream) {
  const float* af    = (const float*)d_in[0];
  const int*   pidx  = (const int*)  d_in[1];
  const float* W1    = (const float*)d_in[2];
  const float* b1    = (const float*)d_in[3];
  const float* Wm    = (const float*)d_in[4];
  const float* bm    = (const float*)d_in[5];
  const float* att_w = (const float*)d_in[6];
  const float* dag_w = (const float*)d_in[7];
  const float* Wf    = (const float*)d_in[8];
  const float* bf    = (const float*)d_in[9];
  float* out  = (float*)d_out;
  float* sink = (float*)d_ws;      // 256*104 floats

  constexpr size_t SMEM1 = (size_t)(208 * 112 + 104 * 68 + 64 * 104 + 112 + 104 + 512) * 4;
  constexpr size_t SMEM2 = (size_t)(256 * 104 + 104) * 4;

  // Opt-in to >64KB dynamic LDS (capture-safe host call, idempotent).
  hipFuncSetAttribute((const void*)scan_kernel,
                      hipFuncAttributeMaxDynamicSharedMemorySize, (int)SMEM1);
  hipFuncSetAttribute((const void*)final_kernel,
                      hipFuncAttributeMaxDynamicSharedMemorySize, (int)SMEM2);

  scan_kernel<<<Dn, TPB, SMEM1, stream>>>(af, pidx, W1, b1, Wm, bm, att_w, sink);
  final_kernel<<<1, 512, SMEM2, stream>>>(sink, dag_w, Wf, bf, out);
}

// Round 3
// 518.554 us; speedup vs baseline: 2.3940x; 2.3940x over previous
//
#include <hip/hip_runtime.h>
#include <cstddef>

// Problem constants
#define Dn 256
#define Ln 64
#define Kn 64
#define Pn 8
#define Fn 104
#define Cn 500
#define KF 6656          // Kn*Fn
#define TPB 448          // 7 waves = 7 n-tiles of 16 cols (112 >= 104)
#define PSTR 108         // PREV row stride in floats (104 padded; 4*108 % 32 = 16 -> <=2-way)
#define XROWB 512        // X bf16-plane row stride in BYTES (32 chunks of 16B; 224 cols used)
#define NQ 1664          // Kn * (Fn/4) quads

typedef __attribute__((ext_vector_type(8))) short bh8;     // 8 bf16 (4 VGPRs) MFMA frag
typedef __attribute__((ext_vector_type(4))) float f32x4;   // MFMA accumulator

__device__ __forceinline__ unsigned short f2bf(float x) {  // RNE f32->bf16
  unsigned u = __builtin_bit_cast(unsigned, x);
  u = (u + 0x7fffu + ((u >> 16) & 1u)) >> 16;
  return (unsigned short)u;
}
__device__ __forceinline__ float bf2f(unsigned short h) {
  unsigned u = ((unsigned)h) << 16;
  return __builtin_bit_cast(float, u);
}

// Stage X[k][c0..c0+3] into hi/lo bf16 planes. c0 % 4 == 0 and (c0 & 7) in {0,4}.
// Swizzle: 16B chunk index (c0>>3) XOR'd with (k&7); row stride 512B (32 chunks).
__device__ __forceinline__ void stage_quad(char* XAc, char* XBc, int k, int c0,
                                           float v0, float v1, float v2, float v3) {
  unsigned short h0 = f2bf(v0), h1 = f2bf(v1), h2 = f2bf(v2), h3 = f2bf(v3);
  unsigned short l0 = f2bf(v0 - bf2f(h0)), l1 = f2bf(v1 - bf2f(h1));
  unsigned short l2 = f2bf(v2 - bf2f(h2)), l3 = f2bf(v3 - bf2f(h3));
  uint2 hv, lv;
  hv.x = (unsigned)h0 | ((unsigned)h1 << 16); hv.y = (unsigned)h2 | ((unsigned)h3 << 16);
  lv.x = (unsigned)l0 | ((unsigned)l1 << 16); lv.y = (unsigned)l2 | ((unsigned)l3 << 16);
  const int off = k * XROWB + ((((c0 >> 3) ^ (k & 7)) << 4) | ((c0 & 7) << 1));
  *reinterpret_cast<uint2*>(XAc + off) = hv;
  *reinterpret_cast<uint2*>(XBc + off) = lv;
}

// Load W^T fragments (hi+lo) into registers. Wave owns n-tile = cols [nt*16, nt*16+16).
// Frag layout (16x16x32 bf16 B-operand): lane l holds col=(l&15), k = kt*32 + (l>>4)*8 + v.
__device__ __forceinline__ void load_w_frags(const float* __restrict__ Wg, int Krows,
                                             int col, int e, bh8* Wh, bh8* Wl) {
  #pragma unroll
  for (int kt = 0; kt < 7; ++kt) {
    bh8 h, l;
    #pragma unroll
    for (int v = 0; v < 8; ++v) {
      int k = kt * 32 + e * 8 + v;
      float x = (k < Krows && col < Fn) ? Wg[k * Fn + col] : 0.f;
      unsigned short hh = f2bf(x);
      unsigned short ll = f2bf(x - bf2f(hh));
      h[v] = (short)hh; l[v] = (short)ll;
    }
    Wh[kt] = h; Wl[kt] = l;
  }
}

// Split-bf16 MFMA GEMM: PREV[0:64, col] = relu(X @ W + b) for this wave's n-tile.
// X = (XA + XB) as bf16 planes, K = 224 (208 used), M = 64 (4 m-tiles).
__device__ __forceinline__ void mfma_gemm(const char* XAc, const char* XBc,
                                          const bh8* Wh, const bh8* Wl,
                                          const float* bms, float* PREVs,
                                          int lane, int col) {
  const int e = lane >> 4;         // 0..3
  const int rb = lane & 15;        // row within m-tile
  const float bias = (col < Fn) ? bms[col] : 0.f;
  f32x4 acc[4];
  #pragma unroll
  for (int mt = 0; mt < 4; ++mt) { f32x4 b4 = {bias, bias, bias, bias}; acc[mt] = b4; }
  #pragma unroll
  for (int kt = 0; kt < 7; ++kt) {
    #pragma unroll
    for (int mt = 0; mt < 4; ++mt) {
      const int r = mt * 16 + rb;
      const int chunk = (kt * 4 + e) ^ (rb & 7);
      const bh8 ah = *reinterpret_cast<const bh8*>(XAc + r * XROWB + chunk * 16);
      const bh8 al = *reinterpret_cast<const bh8*>(XBc + r * XROWB + chunk * 16);
      acc[mt] = __builtin_amdgcn_mfma_f32_16x16x32_bf16(ah, Wh[kt], acc[mt], 0, 0, 0);
      acc[mt] = __builtin_amdgcn_mfma_f32_16x16x32_bf16(al, Wh[kt], acc[mt], 0, 0, 0);
      acc[mt] = __builtin_amdgcn_mfma_f32_16x16x32_bf16(ah, Wl[kt], acc[mt], 0, 0, 0);
      acc[mt] = __builtin_amdgcn_mfma_f32_16x16x32_bf16(al, Wl[kt], acc[mt], 0, 0, 0);
    }
  }
  // Epilogue: relu, write PREV. C layout: row = mt*16 + (lane>>4)*4 + j, col = lane&15 (+n0).
  if (col < Fn) {
    #pragma unroll
    for (int mt = 0; mt < 4; ++mt) {
      #pragma unroll
      for (int j = 0; j < 4; ++j) {
        int r = mt * 16 + e * 4 + j;
        PREVs[r * PSTR + col] = fmaxf(acc[mt][j], 0.f);
      }
    }
  }
}

// Persistent scan kernel: one block per d, l = 0..63 internal.
__global__ __launch_bounds__(TPB) void scan_kernel(
    const float* __restrict__ af,     // (D, L, K, F)
    const int*   __restrict__ pidx,   // (D, L-1, K, P)
    const float* __restrict__ W1, const float* __restrict__ b1,
    const float* __restrict__ Wm, const float* __restrict__ bm,
    const float* __restrict__ att_w,
    float* __restrict__ sink)         // (D, F)
{
  extern __shared__ char smem[];
  char*  XAc   = smem;                          // 32768 B  (hi plane, 64 rows x 512B)
  char*  XBc   = smem + 32768;                  // 32768 B  (lo plane)
  float* PREVs = (float*)(smem + 65536);        // 64*108*4 = 27648 B
  float* bms   = (float*)(smem + 65536 + 27648);         // 112 floats
  float* aws   = (float*)(smem + 65536 + 27648 + 448);   // 104 floats
  int*   idxs  = (int*)  (smem + 65536 + 27648 + 448 + 416); // 512 ints
  // total = 96096 B

  const int t = threadIdx.x;
  const int d = blockIdx.x;
  const int lane = t & 63;
  const int nt = t >> 6;                // wave = n-tile 0..6
  const int e = lane >> 4;
  const int col = nt * 16 + (lane & 15);

  const float*  afd = af + (size_t)d * (Ln * KF);
  const float4* af4 = reinterpret_cast<const float4*>(afd);
  const int*    pid = pidx + (size_t)d * ((Ln - 1) * Kn * Pn);

  bh8 Wh[7], Wl[7];
  float4 pf4[4];
  int ir0 = 0, ir1 = 0;

  // ---- init: zero both X planes (pad cols stay 0 forever), stage b1/att_w ----
  for (int i = t; i < 16384; i += TPB) reinterpret_cast<unsigned*>(XAc)[i] = 0u;
  if (t < Fn) { bms[t] = b1[t]; aws[t] = att_w[t]; }
  else if (t < 112) bms[t] = 0.f;
  load_w_frags(W1, Fn, col, e, Wh, Wl);
  // stage atoms0 at X cols 0..103
  #pragma unroll
  for (int j = 0; j < 4; ++j) {
    int q = t + j * TPB;
    if (q < NQ) {
      int k = q / 26, fq = (q - k * 26) << 2;
      float4 v = af4[q];
      stage_quad(XAc, XBc, k, fq, v.x, v.y, v.z, v.w);
    }
  }
  __syncthreads();

  // ---- step 0: PREV = relu(atoms0 @ W1 + b1) ----
  mfma_gemm(XAc, XBc, Wh, Wl, bms, PREVs, lane, col);
  __syncthreads();

  // ---- restage: Wm frags, bm, idx block 0, prefetch atoms block 1 ----
  load_w_frags(Wm, 2 * Fn, col, e, Wh, Wl);
  if (t < Fn) bms[t] = bm[t];
  idxs[t] = pid[t];
  if (t < 64) idxs[TPB + t] = pid[TPB + t];
  #pragma unroll
  for (int j = 0; j < 4; ++j) {
    int q = t + j * TPB;
    if (q < NQ) pf4[j] = af4[NQ + q];
  }
  __syncthreads();

  // ---- main scan: l = 1..63 ----
  for (int l = 1; l < Ln; ++l) {
    // Phase A1: stage atoms(l) from prefetch regs at X cols 104..207
    #pragma unroll
    for (int j = 0; j < 4; ++j) {
      int q = t + j * TPB;
      if (q < NQ) {
        int k = q / 26, fq = (q - k * 26) << 2;
        float4 v = pf4[j];
        stage_quad(XAc, XBc, k, Fn + fq, v.x, v.y, v.z, v.w);
      }
    }
    // Phase A2: issue prefetches for l+1 (land during gather+GEMM)
    if (l < 63) {
      const float4* an = af4 + (size_t)(l + 1) * NQ;
      #pragma unroll
      for (int j = 0; j < 4; ++j) {
        int q = t + j * TPB;
        if (q < NQ) pf4[j] = an[q];
      }
      const int* pn = pid + (size_t)l * 512;
      ir0 = pn[t];
      if (t < 64) ir1 = pn[TPB + t];
    }
    // Phase A3: gather + softmax(P) + aggregate -> X cols 0..103
    for (int q = t; q < NQ; q += TPB) {
      int k = q / 26, fq = (q - k * 26) << 2;
      const float4 w4 = *reinterpret_cast<const float4*>(aws + fq);
      const float wa[4] = {w4.x, w4.y, w4.z, w4.w};
      float vv[8][4];
      #pragma unroll
      for (int p = 0; p < Pn; ++p) {
        int ip = idxs[(k << 3) + p];
        float4 v4 = *reinterpret_cast<const float4*>(PREVs + ip * PSTR + fq);
        vv[p][0] = v4.x; vv[p][1] = v4.y; vv[p][2] = v4.z; vv[p][3] = v4.w;
      }
      float ag[4];
      #pragma unroll
      for (int c = 0; c < 4; ++c) {
        float m = -3.0e38f;
        #pragma unroll
        for (int p = 0; p < Pn; ++p) m = fmaxf(m, wa[c] * vv[p][c]);
        float es = 0.f, ps = 0.f;
        #pragma unroll
        for (int p = 0; p < Pn; ++p) {
          float ex = __expf(wa[c] * vv[p][c] - m);
          es += ex; ps += ex * vv[p][c];
        }
        ag[c] = ps / es;
      }
      stage_quad(XAc, XBc, k, fq, ag[0], ag[1], ag[2], ag[3]);
    }
    __syncthreads();

    // Phase B: MFMA GEMM + relu epilogue -> PREV; stage idx for l+1
    mfma_gemm(XAc, XBc, Wh, Wl, bms, PREVs, lane, col);
    if (l < 63) {
      idxs[t] = ir0;
      if (t < 64) idxs[TPB + t] = ir1;
    }
    __syncthreads();
  }

  // sink = last[:, K-1]
  if (t < Fn) sink[d * Fn + t] = PREVs[(Kn - 1) * PSTR + t];
}

// Final: DAG softmax over D, pool, project to C.
__global__ __launch_bounds__(512) void final_kernel(
    const float* __restrict__ sink, const float* __restrict__ dag_w,
    const float* __restrict__ Wf, const float* __restrict__ bf,
    float* __restrict__ out)
{
  extern __shared__ char smem[];
  float* ss = (float*)smem;       // 256*104
  float* pooled = ss + Dn * Fn;   // 104
  const int t = threadIdx.x;
  for (int i = t; i < Dn * Fn; i += 512) ss[i] = sink[i];
  __syncthreads();
  if (t < Fn) {
    float wv = dag_w[t];
    float m = -3.0e38f;
    for (int dd = 0; dd < Dn; ++dd) m = fmaxf(m, wv * ss[dd * Fn + t]);
    float es = 0.f, ps = 0.f;
    for (int dd = 0; dd < Dn; ++dd) {
      float v = ss[dd * Fn + t];
      float ex = __expf(wv * v - m);
      es += ex; ps += ex * v;
    }
    pooled[t] = ps / es;
  }
  __syncthreads();
  if (t < Cn) {
    float a = bf[t];
    for (int f = 0; f < Fn; ++f) a = fmaf(pooled[f], Wf[f * Cn + t], a);
    out[t] = a;
  }
}

extern "C" void kernel_launch(void* const* d_in, const int* in_sizes, int n_in,
                              void* d_out, int out_size, void* d_ws, size_t ws_size,
                              hipStream_t stream) {
  const float* af    = (const float*)d_in[0];
  const int*   pidx  = (const int*)  d_in[1];
  const float* W1    = (const float*)d_in[2];
  const float* b1    = (const float*)d_in[3];
  const float* Wm    = (const float*)d_in[4];
  const float* bm    = (const float*)d_in[5];
  const float* att_w = (const float*)d_in[6];
  const float* dag_w = (const float*)d_in[7];
  const float* Wf    = (const float*)d_in[8];
  const float* bf    = (const float*)d_in[9];
  float* out  = (float*)d_out;
  float* sink = (float*)d_ws;      // 256*104 floats

  constexpr size_t SMEM1 = 96096;
  constexpr size_t SMEM2 = (size_t)(Dn * Fn + Fn) * 4;

  (void)hipFuncSetAttribute((const void*)scan_kernel,
                      hipFuncAttributeMaxDynamicSharedMemorySize, (int)SMEM1);
  (void)hipFuncSetAttribute((const void*)final_kernel,
                      hipFuncAttributeMaxDynamicSharedMemorySize, (int)SMEM2);

  scan_kernel<<<Dn, TPB, SMEM1, stream>>>(af, pidx, W1, b1, Wm, bm, att_w, sink);
  final_kernel<<<1, 512, SMEM2, stream>>>(sink, dag_w, Wf, bf, out);
}

// Round 4
// 364.270 us; speedup vs baseline: 3.4079x; 1.4235x over previous
//
#include <hip/hip_runtime.h>
#include <cstddef>

// Problem constants
#define Dn 256
#define Ln 64
#define Kn 64
#define Pn 8
#define Fn 104
#define Cn 500
#define KF 6656          // Kn*Fn
#define TPB 896          // 14 waves = 7 n-tiles x 2 M-halves
#define PSTR 108         // PREV row stride in floats
#define XROWB 512        // X bf16-plane row stride in BYTES (32 chunks of 16B)
#define NQ 1664          // Kn * (Fn/4) quads

typedef __attribute__((ext_vector_type(8))) short bh8;     // 8 bf16 (4 VGPRs) MFMA frag
typedef __attribute__((ext_vector_type(4))) float f32x4;   // MFMA accumulator

__device__ __forceinline__ unsigned short f2bf_rne(float x) {  // RNE f32->bf16 (cold paths)
  unsigned u = __builtin_bit_cast(unsigned, x);
  u = (u + 0x7fffu + ((u >> 16) & 1u)) >> 16;
  return (unsigned short)u;
}
__device__ __forceinline__ float bf2f(unsigned short h) {
  unsigned u = ((unsigned)h) << 16;
  return __builtin_bit_cast(float, u);
}
// Pack bf16(a)|bf16(b)<<16 with RTZ via one v_perm_b32.
__device__ __forceinline__ unsigned pkhi(float a, float b) {
  return __builtin_amdgcn_perm(__builtin_bit_cast(unsigned, b),
                               __builtin_bit_cast(unsigned, a), 0x07060302u);
}
__device__ __forceinline__ float hi_of(float x) {
  return __builtin_bit_cast(float, __builtin_bit_cast(unsigned, x) & 0xffff0000u);
}

// Stage X[k][c0..c0+3] into hi/lo bf16 planes (RTZ split). (c0 & 3) == 0.
// Swizzle: 16B chunk index (c0>>3) XOR'd with (k&7); row stride 512B.
__device__ __forceinline__ void stage_quad(char* XAc, char* XBc, int k, int c0,
                                           float v0, float v1, float v2, float v3) {
  uint2 hv, lv;
  hv.x = pkhi(v0, v1); hv.y = pkhi(v2, v3);
  const float r0 = v0 - hi_of(v0), r1 = v1 - hi_of(v1);
  const float r2 = v2 - hi_of(v2), r3 = v3 - hi_of(v3);
  lv.x = pkhi(r0, r1); lv.y = pkhi(r2, r3);
  const int off = k * XROWB + ((((c0 >> 3) ^ (k & 7)) << 4) | ((c0 & 7) << 1));
  *reinterpret_cast<uint2*>(XAc + off) = hv;
  *reinterpret_cast<uint2*>(XBc + off) = lv;
}

// Load W^T fragments (hi+lo, RNE — cold path) into registers.
// B-frag layout (16x16x32 bf16): lane l holds col=(l&15), k = kt*32 + (l>>4)*8 + v.
__device__ __forceinline__ void load_w_frags(const float* __restrict__ Wg, int Krows,
                                             int col, int e, bh8* Wh, bh8* Wl) {
  #pragma unroll
  for (int kt = 0; kt < 7; ++kt) {
    bh8 h, l;
    #pragma unroll
    for (int v = 0; v < 8; ++v) {
      int k = kt * 32 + e * 8 + v;
      float x = (k < Krows && col < Fn) ? Wg[k * Fn + col] : 0.f;
      unsigned short hh = f2bf_rne(x);
      unsigned short ll = f2bf_rne(x - bf2f(hh));
      h[v] = (short)hh; l[v] = (short)ll;
    }
    Wh[kt] = h; Wl[kt] = l;
  }
}

// Split-bf16 MFMA GEMM. Wave handles n-tile (col) x M-half mh (rows mh*32..mh*32+31).
__device__ __forceinline__ void mfma_gemm(const char* XAc, const char* XBc,
                                          const bh8* Wh, const bh8* Wl,
                                          const float* bms, float* PREVs,
                                          int lane, int col, int mh) {
  const int e = lane >> 4;         // 0..3
  const int rb = lane & 15;        // row within m-tile
  const float bias = (col < Fn) ? bms[col] : 0.f;
  f32x4 acc[2];
  #pragma unroll
  for (int mti = 0; mti < 2; ++mti) { f32x4 b4 = {bias, bias, bias, bias}; acc[mti] = b4; }
  #pragma unroll
  for (int kt = 0; kt < 7; ++kt) {
    #pragma unroll
    for (int mti = 0; mti < 2; ++mti) {
      const int r = (mh * 2 + mti) * 16 + rb;
      const int chunk = (kt * 4 + e) ^ (rb & 7);
      const bh8 ah = *reinterpret_cast<const bh8*>(XAc + r * XROWB + chunk * 16);
      const bh8 al = *reinterpret_cast<const bh8*>(XBc + r * XROWB + chunk * 16);
      acc[mti] = __builtin_amdgcn_mfma_f32_16x16x32_bf16(ah, Wh[kt], acc[mti], 0, 0, 0);
      acc[mti] = __builtin_amdgcn_mfma_f32_16x16x32_bf16(al, Wh[kt], acc[mti], 0, 0, 0);
      acc[mti] = __builtin_amdgcn_mfma_f32_16x16x32_bf16(ah, Wl[kt], acc[mti], 0, 0, 0);
      acc[mti] = __builtin_amdgcn_mfma_f32_16x16x32_bf16(al, Wl[kt], acc[mti], 0, 0, 0);
    }
  }
  // C layout: row = mt*16 + (lane>>4)*4 + j, col = lane&15 (+nt*16).
  if (col < Fn) {
    #pragma unroll
    for (int mti = 0; mti < 2; ++mti) {
      #pragma unroll
      for (int j = 0; j < 4; ++j) {
        int r = (mh * 2 + mti) * 16 + e * 4 + j;
        PREVs[r * PSTR + col] = fmaxf(acc[mti][j], 0.f);
      }
    }
  }
}

// Persistent scan kernel: one block per d, l = 0..63 internal.
__global__ __launch_bounds__(TPB) void scan_kernel(
    const float* __restrict__ af,     // (D, L, K, F)
    const int*   __restrict__ pidx,   // (D, L-1, K, P)
    const float* __restrict__ W1, const float* __restrict__ b1,
    const float* __restrict__ Wm, const float* __restrict__ bm,
    const float* __restrict__ att_w,
    float* __restrict__ sink)         // (D, F)
{
  extern __shared__ char smem[];
  char*  XAc   = smem;                          // 32768 B  (hi plane, 64 rows x 512B)
  char*  XBc   = smem + 32768;                  // 32768 B  (lo plane)
  float* PREVs = (float*)(smem + 65536);        // 64*108*4 = 27648 B
  float* bms   = (float*)(smem + 65536 + 27648);         // 112 floats
  float* aws   = (float*)(smem + 65536 + 27648 + 448);   // 104 floats
  int*   idxs  = (int*)  (smem + 65536 + 27648 + 448 + 416); // 512 ints (16B aligned)
  // total = 96096 B

  const int t = threadIdx.x;
  const int d = blockIdx.x;
  const int lane = t & 63;
  const int wv = t >> 6;                // 0..13
  const int nt = wv % 7;                // n-tile
  const int mh = wv / 7;                // M-half
  const int e = lane >> 4;
  const int col = nt * 16 + (lane & 15);

  const float*  afd = af + (size_t)d * (Ln * KF);
  const float4* af4 = reinterpret_cast<const float4*>(afd);
  const int*    pid = pidx + (size_t)d * ((Ln - 1) * Kn * Pn);

  bh8 Wh[7], Wl[7];
  float4 pf4[2];
  int ir0 = 0;

  // ---- init: zero both X planes (pad cols stay 0 forever), stage b1/att_w ----
  for (int i = t; i < 16384; i += TPB) reinterpret_cast<unsigned*>(XAc)[i] = 0u;
  if (t < Fn) { bms[t] = b1[t]; aws[t] = att_w[t]; }
  else if (t < 112) bms[t] = 0.f;
  load_w_frags(W1, Fn, col, e, Wh, Wl);
  // stage atoms0 at X cols 0..103
  #pragma unroll
  for (int j = 0; j < 2; ++j) {
    int q = t + j * TPB;
    if (q < NQ) {
      int k = q / 26, fq = (q - k * 26) << 2;
      float4 v = af4[q];
      stage_quad(XAc, XBc, k, fq, v.x, v.y, v.z, v.w);
    }
  }
  __syncthreads();

  // ---- step 0: PREV = relu(atoms0 @ W1 + b1) ----
  mfma_gemm(XAc, XBc, Wh, Wl, bms, PREVs, lane, col, mh);
  __syncthreads();

  // ---- restage: Wm frags, bm, idx block 0, prefetch atoms block 1 ----
  load_w_frags(Wm, 2 * Fn, col, e, Wh, Wl);
  if (t < Fn) bms[t] = bm[t];
  if (t < 512) idxs[t] = pid[t];
  #pragma unroll
  for (int j = 0; j < 2; ++j) {
    int q = t + j * TPB;
    if (q < NQ) pf4[j] = af4[NQ + q];
  }
  __syncthreads();

  // ---- main scan: l = 1..63 ----
  for (int l = 1; l < Ln; ++l) {
    // Phase A1: stage atoms(l) from prefetch regs at X cols 104..207
    #pragma unroll
    for (int j = 0; j < 2; ++j) {
      int q = t + j * TPB;
      if (q < NQ) {
        int k = q / 26, fq = (q - k * 26) << 2;
        float4 v = pf4[j];
        stage_quad(XAc, XBc, k, Fn + fq, v.x, v.y, v.z, v.w);
      }
    }
    // Phase A2: issue prefetches for l+1 (land during gather+GEMM)
    if (l < 63) {
      const float4* an = af4 + (size_t)(l + 1) * NQ;
      #pragma unroll
      for (int j = 0; j < 2; ++j) {
        int q = t + j * TPB;
        if (q < NQ) pf4[j] = an[q];
      }
      if (t < 512) ir0 = pid[(size_t)l * 512 + t];
    }
    // Phase A3: gather + softmax(P) + aggregate -> X cols 0..103
    for (int q = t; q < NQ; q += TPB) {
      int k = q / 26, fq = (q - k * 26) << 2;
      const float4 w4 = *reinterpret_cast<const float4*>(aws + fq);
      const float wa[4] = {w4.x, w4.y, w4.z, w4.w};
      const int4 ia = *reinterpret_cast<const int4*>(idxs + (k << 3));
      const int4 ib = *reinterpret_cast<const int4*>(idxs + (k << 3) + 4);
      const int ip[8] = {ia.x, ia.y, ia.z, ia.w, ib.x, ib.y, ib.z, ib.w};
      float vv[8][4];
      #pragma unroll
      for (int p = 0; p < Pn; ++p) {
        float4 v4 = *reinterpret_cast<const float4*>(PREVs + ip[p] * PSTR + fq);
        vv[p][0] = v4.x; vv[p][1] = v4.y; vv[p][2] = v4.z; vv[p][3] = v4.w;
      }
      float ag[4];
      #pragma unroll
      for (int c = 0; c < 4; ++c) {
        float vmax = vv[0][c];
        #pragma unroll
        for (int p = 1; p < Pn; ++p) vmax = fmaxf(vmax, vv[p][c]);
        const float m = wa[c] * vmax;     // att_w >= 0 -> max(wa*v) = wa*max(v)
        float es = 0.f, ps = 0.f;
        #pragma unroll
        for (int p = 0; p < Pn; ++p) {
          float ex = __expf(fmaf(wa[c], vv[p][c], -m));
          es += ex; ps += ex * vv[p][c];
        }
        ag[c] = ps * __builtin_amdgcn_rcpf(es);   // es >= 1
      }
      stage_quad(XAc, XBc, k, fq, ag[0], ag[1], ag[2], ag[3]);
    }
    __syncthreads();

    // Phase B: MFMA GEMM + relu epilogue -> PREV; stage idx for l+1
    mfma_gemm(XAc, XBc, Wh, Wl, bms, PREVs, lane, col, mh);
    if (l < 63 && t < 512) idxs[t] = ir0;
    __syncthreads();
  }

  // sink = last[:, K-1]
  if (t < Fn) sink[d * Fn + t] = PREVs[(Kn - 1) * PSTR + t];
}

// Final: DAG softmax over D, pool, project to C.
__global__ __launch_bounds__(512) void final_kernel(
    const float* __restrict__ sink, const float* __restrict__ dag_w,
    const float* __restrict__ Wf, const float* __restrict__ bf,
    float* __restrict__ out)
{
  extern __shared__ char smem[];
  float* ss = (float*)smem;       // 256*104
  float* pooled = ss + Dn * Fn;   // 104
  const int t = threadIdx.x;
  for (int i = t; i < Dn * Fn; i += 512) ss[i] = sink[i];
  __syncthreads();
  if (t < Fn) {
    float wvv = dag_w[t];
    float m = -3.0e38f;
    for (int dd = 0; dd < Dn; ++dd) m = fmaxf(m, wvv * ss[dd * Fn + t]);
    float es = 0.f, ps = 0.f;
    for (int dd = 0; dd < Dn; ++dd) {
      float v = ss[dd * Fn + t];
      float ex = __expf(wvv * v - m);
      es += ex; ps += ex * v;
    }
    pooled[t] = ps / es;
  }
  __syncthreads();
  if (t < Cn) {
    float a = bf[t];
    for (int f = 0; f < Fn; ++f) a = fmaf(pooled[f], Wf[f * Cn + t], a);
    out[t] = a;
  }
}

extern "C" void kernel_launch(void* const* d_in, const int* in_sizes, int n_in,
                              void* d_out, int out_size, void* d_ws, size_t ws_size,
                              hipStream_t stream) {
  const float* af    = (const float*)d_in[0];
  const int*   pidx  = (const int*)  d_in[1];
  const float* W1    = (const float*)d_in[2];
  const float* b1    = (const float*)d_in[3];
  const float* Wm    = (const float*)d_in[4];
  const float* bm    = (const float*)d_in[5];
  const float* att_w = (const float*)d_in[6];
  const float* dag_w = (const float*)d_in[7];
  const float* Wf    = (const float*)d_in[8];
  const float* bf    = (const float*)d_in[9];
  float* out  = (float*)d_out;
  float* sink = (float*)d_ws;      // 256*104 floats

  constexpr size_t SMEM1 = 96096;
  constexpr size_t SMEM2 = (size_t)(Dn * Fn + Fn) * 4;

  (void)hipFuncSetAttribute((const void*)scan_kernel,
                      hipFuncAttributeMaxDynamicSharedMemorySize, (int)SMEM1);
  (void)hipFuncSetAttribute((const void*)final_kernel,
                      hipFuncAttributeMaxDynamicSharedMemorySize, (int)SMEM2);

  scan_kernel<<<Dn, TPB, SMEM1, stream>>>(af, pidx, W1, b1, Wm, bm, att_w, sink);
  final_kernel<<<1, 512, SMEM2, stream>>>(sink, dag_w, Wf, bf, out);
}